// Round 2
// baseline (521.315 us; speedup 1.0000x reference)
//
#include <hip/hip_runtime.h>
#include <cstddef>

// Problem constants (fixed by setup_inputs)
#define B_  4
#define L_  1024
#define H_  8
#define DK_ 32
#define DV_ 32
#define BH_ 32            // B_*H_
#define HD_ 256           // H_*DK_

#define INV_T 0.17677669529663687f  // 1/sqrt(32)

// ---------------------------------------------------------------------------
// Kernel 0: transpose q[b, j, h*32+d] -> qT[bh][d4][j][c]  (c = d%4)
// so score reads ONE dwordx4 per (d4, j) instead of 4 strided dwords.
// grid 128 = bh(32) x jt(4), 256 threads
// ---------------------------------------------------------------------------
__global__ __launch_bounds__(256) void transpose_q(
    const float* __restrict__ q, float* __restrict__ qT)
{
    const int bh  = blockIdx.x >> 2;
    const int jt  = blockIdx.x & 3;
    const int b   = bh >> 3, h = bh & 7;
    const int tid = threadIdx.x;

    __shared__ float t_s[256][33];

    const float* qb = q + (size_t)b * L_ * HD_ + h * DK_;
    #pragma unroll
    for (int rep = 0; rep < 8; ++rep) {
        const int f = rep * 1024 + tid * 4;
        const int j = f >> 5, d = f & 31;
        float4 val = *reinterpret_cast<const float4*>(qb + (size_t)(jt * 256 + j) * HD_ + d);
        t_s[j][d + 0] = val.x; t_s[j][d + 1] = val.y;
        t_s[j][d + 2] = val.z; t_s[j][d + 3] = val.w;
    }
    __syncthreads();
    // qT[bh][d4][j][c] : bh*32768 + d4*4096 + j*4 + c
    float* qo = qT + (size_t)bh * (DK_ * L_);
    const int j = jt * 256 + tid;
    #pragma unroll
    for (int d4 = 0; d4 < 8; ++d4) {
        float4 w = make_float4(t_s[tid][d4 * 4 + 0], t_s[tid][d4 * 4 + 1],
                               t_s[tid][d4 * 4 + 2], t_s[tid][d4 * 4 + 3]);
        *reinterpret_cast<float4*>(qo + (size_t)d4 * (L_ * 4) + (size_t)j * 4) = w;
    }
}

// ---------------------------------------------------------------------------
// Kernel 1: scores. grid 1024 = ig(256) x half(2) x jhalf(2).
// Block: 4 i's x 16 bh x 512 j's. 256 thr = 4 waves; wave w -> bh w*4..w*4+3.
// k is wave-uniform -> scalar loads (SGPR broadcast), no k LDS.
// a_k tile is reg-prefetched (T14 async-stage split): next tile's global
// loads issue before the current tile's compute; ds_write after barrier.
// Writes u = exp(score/T) + per-row partial sums (per jhalf).
// ---------------------------------------------------------------------------
__global__ __launch_bounds__(256) void score_kernel(
    const float* __restrict__ qT,
    const float* __restrict__ k,
    const float* __restrict__ a_k,
    float* __restrict__ attn_u,
    float* __restrict__ sums)   // [2][BH_][L_] partials
{
    const int bidx  = blockIdx.x;
    const int jhalf = bidx & 1;
    const int half  = (bidx >> 1) & 1;
    const int ig    = bidx >> 2;
    const int i0    = ig * 4;
    const int bh0   = half * 16;
    const int tid   = threadIdx.x;
    const int w     = __builtin_amdgcn_readfirstlane(tid >> 6);  // force wave-uniform
    const int lane  = tid & 63;

    __shared__ float a_s[4][64][36];   // [ii][jj][d] pad 36 (b128 conflict-free)

    float rs[4][4] = {{0.f}};          // [bhl][ii] row-sum partials
    float4 st[8];                      // staging regs for a_k tile

    const int jt0 = jhalf * 8, jtE = jt0 + 8;

    // prologue: stage tile jt0
    #pragma unroll
    for (int rep = 0; rep < 8; ++rep) {
        const int f  = rep * 1024 + tid * 4;
        const int ii = f >> 11, jj = (f >> 5) & 63, d = f & 31;
        st[rep] = *reinterpret_cast<const float4*>(
            a_k + (size_t)(i0 + ii) * (L_ * DK_) + (size_t)(jt0 * 64 + jj) * DK_ + d);
    }
    #pragma unroll
    for (int rep = 0; rep < 8; ++rep) {
        const int f  = rep * 1024 + tid * 4;
        const int ii = f >> 11, jj = (f >> 5) & 63, d = f & 31;
        *reinterpret_cast<float4*>(&a_s[ii][jj][d]) = st[rep];
    }
    __syncthreads();

    for (int jt = jt0; jt < jtE; ++jt) {
        const int j0   = jt * 64;
        const bool more = (jt != jtE - 1);

        // issue next tile's loads early — latency hides under compute
        if (more) {
            #pragma unroll
            for (int rep = 0; rep < 8; ++rep) {
                const int f  = rep * 1024 + tid * 4;
                const int ii = f >> 11, jj = (f >> 5) & 63, d = f & 31;
                st[rep] = *reinterpret_cast<const float4*>(
                    a_k + (size_t)(i0 + ii) * (L_ * DK_) + (size_t)(j0 + 64 + jj) * DK_ + d);
            }
        }

        float s[4][4];
        #pragma unroll
        for (int bhl = 0; bhl < 4; ++bhl)
            #pragma unroll
            for (int ii = 0; ii < 4; ++ii) s[bhl][ii] = 0.f;

        #pragma unroll 2
        for (int d4 = 0; d4 < 8; ++d4) {
            float4 av[4];
            #pragma unroll
            for (int ii = 0; ii < 4; ++ii)
                av[ii] = *reinterpret_cast<const float4*>(&a_s[ii][lane][d4 * 4]);
            #pragma unroll
            for (int bhl = 0; bhl < 4; ++bhl) {
                const int bh = bh0 + w * 4 + bhl;      // wave-uniform
                const int b  = bh >> 3, h = bh & 7;
                // qT[bh][d4][j][c] — one dwordx4 per (d4, bhl)
                const float4 q4 = *reinterpret_cast<const float4*>(
                    qT + (size_t)bh * (DK_ * L_) + (size_t)d4 * (L_ * 4) + (size_t)(j0 + lane) * 4);
                const float* kp = k + (size_t)b * L_ * HD_ + (size_t)i0 * HD_ + h * DK_ + d4 * 4;
                #pragma unroll
                for (int ii = 0; ii < 4; ++ii) {
                    float4 kv = *reinterpret_cast<const float4*>(kp + ii * HD_);  // s_load
                    s[bhl][ii] = fmaf(kv.x * av[ii].x, q4.x, s[bhl][ii]);
                    s[bhl][ii] = fmaf(kv.y * av[ii].y, q4.y, s[bhl][ii]);
                    s[bhl][ii] = fmaf(kv.z * av[ii].z, q4.z, s[bhl][ii]);
                    s[bhl][ii] = fmaf(kv.w * av[ii].w, q4.w, s[bhl][ii]);
                }
            }
        }

        #pragma unroll
        for (int bhl = 0; bhl < 4; ++bhl) {
            const int bh = bh0 + w * 4 + bhl;
            #pragma unroll
            for (int ii = 0; ii < 4; ++ii) {
                const float u = __expf(s[bhl][ii] * INV_T);
                rs[bhl][ii] += u;
                attn_u[((size_t)bh * L_ + (i0 + ii)) * L_ + j0 + lane] = u;
            }
        }

        __syncthreads();
        if (more) {
            #pragma unroll
            for (int rep = 0; rep < 8; ++rep) {
                const int f  = rep * 1024 + tid * 4;
                const int ii = f >> 11, jj = (f >> 5) & 63, d = f & 31;
                *reinterpret_cast<float4*>(&a_s[ii][jj][d]) = st[rep];
            }
        }
        __syncthreads();
    }

    #pragma unroll
    for (int bhl = 0; bhl < 4; ++bhl) {
        #pragma unroll
        for (int ii = 0; ii < 4; ++ii) {
            float vsum = rs[bhl][ii];
            #pragma unroll
            for (int off = 32; off > 0; off >>= 1) vsum += __shfl_xor(vsum, off);
            if (lane == 0)
                sums[((size_t)jhalf * BH_ + bh0 + w * 4 + bhl) * L_ + i0 + ii] = vsum;
        }
    }
}

// ---------------------------------------------------------------------------
// Kernel 2: normalize + PV. grid 1024 = bh(32) x ic(32: 32 i-rows each).
// 256 thr: r = tid>>3 (row 0..31), t8 = tid&7 -> 4 dv per lane (b128 v reads).
// u/v tiles reg-prefetched like score.
// ---------------------------------------------------------------------------
__global__ __launch_bounds__(256) void pv_kernel(
    const float* __restrict__ v,
    const float* __restrict__ sums,
    float* __restrict__ attn,    // u on entry, p on exit
    float* __restrict__ out)
{
    const int bh  = blockIdx.x >> 5;
    const int ic  = blockIdx.x & 31;
    const int i0  = ic * 32;
    const int b   = bh >> 3, h = bh & 7;
    const int tid = threadIdx.x;
    const int r   = tid >> 3;          // 0..31 (both compute row and stage row)
    const int t8  = tid & 7;
    const int dv0 = t8 * 4;
    const int c8  = t8 * 8;            // u-stage column start
    const int jv  = tid >> 2;          // v-stage row 0..63
    const int dvs = (tid & 3) * 8;     // v-stage col start

    __shared__ float v_s[64][36];      // [jj][dv] pad 36
    __shared__ float u_s[32][68];      // pad 68: broadcast reads conflict-free

    const float inv = 1.0f / (sums[(size_t)bh * L_ + i0 + r] +
                              sums[(size_t)(BH_ + bh) * L_ + i0 + r]);
    float* arow = attn + ((size_t)bh * L_ + i0 + r) * L_;
    const float* vbase = v + (size_t)b * L_ * HD_ + h * DV_;

    float4 acc = make_float4(0.f, 0.f, 0.f, 0.f);

    float4 u0, u1, v0, v1;
    // prologue: stage tile 0
    u0 = *reinterpret_cast<const float4*>(arow + c8);
    u1 = *reinterpret_cast<const float4*>(arow + c8 + 4);
    v0 = *reinterpret_cast<const float4*>(vbase + (size_t)jv * HD_ + dvs);
    v1 = *reinterpret_cast<const float4*>(vbase + (size_t)jv * HD_ + dvs + 4);
    u0.x *= inv; u0.y *= inv; u0.z *= inv; u0.w *= inv;
    u1.x *= inv; u1.y *= inv; u1.z *= inv; u1.w *= inv;
    *reinterpret_cast<float4*>(&u_s[r][c8])     = u0;
    *reinterpret_cast<float4*>(&u_s[r][c8 + 4]) = u1;
    *reinterpret_cast<float4*>(arow + c8)       = u0;   // write p back
    *reinterpret_cast<float4*>(arow + c8 + 4)   = u1;
    *reinterpret_cast<float4*>(&v_s[jv][dvs])     = v0;
    *reinterpret_cast<float4*>(&v_s[jv][dvs + 4]) = v1;
    __syncthreads();

    for (int jt = 0; jt < 16; ++jt) {
        const int j0 = jt * 64;
        const bool more = (jt != 15);

        if (more) {   // issue next tile's loads — hide under FMAs
            u0 = *reinterpret_cast<const float4*>(arow + j0 + 64 + c8);
            u1 = *reinterpret_cast<const float4*>(arow + j0 + 64 + c8 + 4);
            v0 = *reinterpret_cast<const float4*>(vbase + (size_t)(j0 + 64 + jv) * HD_ + dvs);
            v1 = *reinterpret_cast<const float4*>(vbase + (size_t)(j0 + 64 + jv) * HD_ + dvs + 4);
        }

        #pragma unroll
        for (int jj = 0; jj < 64; ++jj) {
            const float ub = u_s[r][jj];                           // broadcast
            const float4 vv = *reinterpret_cast<const float4*>(&v_s[jj][dv0]);
            acc.x = fmaf(ub, vv.x, acc.x);
            acc.y = fmaf(ub, vv.y, acc.y);
            acc.z = fmaf(ub, vv.z, acc.z);
            acc.w = fmaf(ub, vv.w, acc.w);
        }

        __syncthreads();
        if (more) {
            u0.x *= inv; u0.y *= inv; u0.z *= inv; u0.w *= inv;
            u1.x *= inv; u1.y *= inv; u1.z *= inv; u1.w *= inv;
            *reinterpret_cast<float4*>(&u_s[r][c8])     = u0;
            *reinterpret_cast<float4*>(&u_s[r][c8 + 4]) = u1;
            *reinterpret_cast<float4*>(arow + j0 + 64 + c8)     = u0;   // p
            *reinterpret_cast<float4*>(arow + j0 + 64 + c8 + 4) = u1;
            *reinterpret_cast<float4*>(&v_s[jv][dvs])     = v0;
            *reinterpret_cast<float4*>(&v_s[jv][dvs + 4]) = v1;
        }
        __syncthreads();
    }

    *reinterpret_cast<float4*>(out + ((size_t)bh * L_ + i0 + r) * DV_ + dv0) = acc;
}

extern "C" void kernel_launch(void* const* d_in, const int* in_sizes, int n_in,
                              void* d_out, int out_size, void* d_ws, size_t ws_size,
                              hipStream_t stream) {
    const float* q   = (const float*)d_in[0];
    const float* k   = (const float*)d_in[1];
    const float* v   = (const float*)d_in[2];
    const float* a_k = (const float*)d_in[3];

    float* out  = (float*)d_out;
    float* attn = out + (size_t)BH_ * L_ * DV_;   // out first, attn second

    float* ws   = (float*)d_ws;
    float* sums = ws;                        // 2*32*1024 floats = 256 KB
    float* qT   = ws + 2 * BH_ * L_;         // 4 MB

    transpose_q<<<dim3(128),   dim3(256), 0, stream>>>(q, qT);
    score_kernel<<<dim3(1024), dim3(256), 0, stream>>>(qT, k, a_k, attn, sums);
    pv_kernel<<<dim3(1024),    dim3(256), 0, stream>>>(v, sums, attn, out);
}

// Round 3
// 413.540 us; speedup vs baseline: 1.2606x; 1.2606x over previous
//
#include <hip/hip_runtime.h>
#include <cstddef>

// Problem constants (fixed by setup_inputs)
#define B_  4
#define L_  1024
#define H_  8
#define DK_ 32
#define DV_ 32
#define BH_ 32            // B_*H_
#define HD_ 256           // H_*DK_

#define INV_T 0.17677669529663687f  // 1/sqrt(32)

// ---------------------------------------------------------------------------
// Kernel 0: transpose q[b, j, h*32+d] -> qT[bh][d4][j][c]  (c = d%4)
// so score reads ONE dwordx4 per (d4, j) instead of 4 strided dwords.
// grid 128 = bh(32) x jt(4), 256 threads
// ---------------------------------------------------------------------------
__global__ __launch_bounds__(256) void transpose_q(
    const float* __restrict__ q, float* __restrict__ qT)
{
    const int bh  = blockIdx.x >> 2;
    const int jt  = blockIdx.x & 3;
    const int b   = bh >> 3, h = bh & 7;
    const int tid = threadIdx.x;

    __shared__ float t_s[256][33];

    const float* qb = q + (size_t)b * L_ * HD_ + h * DK_;
    #pragma unroll
    for (int rep = 0; rep < 8; ++rep) {
        const int f = rep * 1024 + tid * 4;
        const int j = f >> 5, d = f & 31;
        float4 val = *reinterpret_cast<const float4*>(qb + (size_t)(jt * 256 + j) * HD_ + d);
        t_s[j][d + 0] = val.x; t_s[j][d + 1] = val.y;
        t_s[j][d + 2] = val.z; t_s[j][d + 3] = val.w;
    }
    __syncthreads();
    // qT[bh][d4][j][c] : bh*32768 + d4*4096 + j*4 + c
    float* qo = qT + (size_t)bh * (DK_ * L_);
    const int j = jt * 256 + tid;
    #pragma unroll
    for (int d4 = 0; d4 < 8; ++d4) {
        float4 w = make_float4(t_s[tid][d4 * 4 + 0], t_s[tid][d4 * 4 + 1],
                               t_s[tid][d4 * 4 + 2], t_s[tid][d4 * 4 + 3]);
        *reinterpret_cast<float4*>(qo + (size_t)d4 * (L_ * 4) + (size_t)j * 4) = w;
    }
}

// ---------------------------------------------------------------------------
// Kernel 1: scores. grid 1024 = ig(256) x half(2) x jhalf(2).
// Block: 4 i's x 16 bh x 512 j's. 256 thr = 4 waves; wave w -> bh w*4..w*4+3.
// k is wave-uniform -> scalar loads (SGPR broadcast), no k LDS.
// a_k staged demand-load -> LDS between barriers (round-1 proven: no spill).
// qT read as one dwordx4 per (d4,bhl) via [bh][d4][j][4] layout.
// Writes u = exp(score/T) + per-row partial sums (per jhalf).
// ---------------------------------------------------------------------------
__global__ __launch_bounds__(256) void score_kernel(
    const float* __restrict__ qT,
    const float* __restrict__ k,
    const float* __restrict__ a_k,
    float* __restrict__ attn_u,
    float* __restrict__ sums)   // [2][BH_][L_] partials
{
    const int bidx  = blockIdx.x;
    const int jhalf = bidx & 1;
    const int half  = (bidx >> 1) & 1;
    const int ig    = bidx >> 2;
    const int i0    = ig * 4;
    const int bh0   = half * 16;
    const int tid   = threadIdx.x;
    const int w     = __builtin_amdgcn_readfirstlane(tid >> 6);  // force wave-uniform
    const int lane  = tid & 63;

    __shared__ float a_s[4][64][36];   // [ii][jj][d] pad 36 (b128 conflict-free)

    float rs[4][4] = {{0.f}};          // [bhl][ii] row-sum partials

    for (int jt = jhalf * 8; jt < jhalf * 8 + 8; ++jt) {
        const int j0 = jt * 64;
        __syncthreads();
        #pragma unroll
        for (int rep = 0; rep < 8; ++rep) {
            const int f  = rep * 1024 + tid * 4;
            const int ii = f >> 11, jj = (f >> 5) & 63, d = f & 31;
            float4 val = *reinterpret_cast<const float4*>(
                a_k + (size_t)(i0 + ii) * (L_ * DK_) + (size_t)(j0 + jj) * DK_ + d);
            *reinterpret_cast<float4*>(&a_s[ii][jj][d]) = val;
        }
        __syncthreads();

        float s[4][4];
        #pragma unroll
        for (int bhl = 0; bhl < 4; ++bhl)
            #pragma unroll
            for (int ii = 0; ii < 4; ++ii) s[bhl][ii] = 0.f;

        #pragma unroll 2
        for (int d4 = 0; d4 < 8; ++d4) {
            float4 av[4];
            #pragma unroll
            for (int ii = 0; ii < 4; ++ii)
                av[ii] = *reinterpret_cast<const float4*>(&a_s[ii][lane][d4 * 4]);
            #pragma unroll
            for (int bhl = 0; bhl < 4; ++bhl) {
                const int bh = bh0 + w * 4 + bhl;      // wave-uniform
                const int b  = bh >> 3, h = bh & 7;
                // qT[bh][d4][j][c] — one dwordx4 per (d4, bhl)
                const float4 q4 = *reinterpret_cast<const float4*>(
                    qT + (size_t)bh * (DK_ * L_) + (size_t)d4 * (L_ * 4) + (size_t)(j0 + lane) * 4);
                const float* kp = k + (size_t)b * L_ * HD_ + (size_t)i0 * HD_ + h * DK_ + d4 * 4;
                #pragma unroll
                for (int ii = 0; ii < 4; ++ii) {
                    float4 kv = *reinterpret_cast<const float4*>(kp + ii * HD_);  // s_load
                    s[bhl][ii] = fmaf(kv.x * av[ii].x, q4.x, s[bhl][ii]);
                    s[bhl][ii] = fmaf(kv.y * av[ii].y, q4.y, s[bhl][ii]);
                    s[bhl][ii] = fmaf(kv.z * av[ii].z, q4.z, s[bhl][ii]);
                    s[bhl][ii] = fmaf(kv.w * av[ii].w, q4.w, s[bhl][ii]);
                }
            }
        }

        #pragma unroll
        for (int bhl = 0; bhl < 4; ++bhl) {
            const int bh = bh0 + w * 4 + bhl;
            #pragma unroll
            for (int ii = 0; ii < 4; ++ii) {
                const float u = __expf(s[bhl][ii] * INV_T);
                rs[bhl][ii] += u;
                attn_u[((size_t)bh * L_ + (i0 + ii)) * L_ + j0 + lane] = u;
            }
        }
    }

    #pragma unroll
    for (int bhl = 0; bhl < 4; ++bhl) {
        #pragma unroll
        for (int ii = 0; ii < 4; ++ii) {
            float vsum = rs[bhl][ii];
            #pragma unroll
            for (int off = 32; off > 0; off >>= 1) vsum += __shfl_xor(vsum, off);
            if (lane == 0)
                sums[((size_t)jhalf * BH_ + bh0 + w * 4 + bhl) * L_ + i0 + ii] = vsum;
        }
    }
}

// ---------------------------------------------------------------------------
// Kernel 2: normalize + PV. grid 2048 = bh(32) x ic(64: 16 i-rows each).
// 256 thr: r = tid>>4 (row 0..15), t16 = tid&15.  (round-1 proven version)
// ---------------------------------------------------------------------------
__global__ __launch_bounds__(256) void pv_kernel(
    const float* __restrict__ v,
    const float* __restrict__ sums,
    float* __restrict__ attn,    // u on entry, p on exit
    float* __restrict__ out)
{
    const int bh  = blockIdx.x >> 6;
    const int ic  = blockIdx.x & 63;
    const int i0  = ic * 16;
    const int b   = bh >> 3, h = bh & 7;
    const int tid = threadIdx.x;
    const int r   = tid >> 4;
    const int t16 = tid & 15;

    __shared__ float v_s[64][36];    // [jj][dv] pad 36
    __shared__ float u_s[16][68];    // pad 68: broadcast reads conflict-free

    const float inv = 1.0f / (sums[(size_t)bh * L_ + i0 + r] +
                              sums[(size_t)(BH_ + bh) * L_ + i0 + r]);
    float* arow = attn + ((size_t)bh * L_ + i0 + r) * L_;

    float a0 = 0.f, a1 = 0.f;

    for (int jt = 0; jt < 16; ++jt) {
        const int j0 = jt * 64;
        __syncthreads();
        {   // stage v tile (64 x 32)
            const int jj = tid >> 2, dv = (tid & 3) * 8;
            const float* vp = v + (size_t)b * L_ * HD_ + (size_t)(j0 + jj) * HD_ + h * DV_ + dv;
            float4 v0 = *reinterpret_cast<const float4*>(vp);
            float4 v1 = *reinterpret_cast<const float4*>(vp + 4);
            *reinterpret_cast<float4*>(&v_s[jj][dv])     = v0;
            *reinterpret_cast<float4*>(&v_s[jj][dv + 4]) = v1;
        }
        {   // stage u tile normalized; write p back
            float4 u0 = *reinterpret_cast<const float4*>(arow + j0 + t16 * 4);
            u0.x *= inv; u0.y *= inv; u0.z *= inv; u0.w *= inv;
            *reinterpret_cast<float4*>(&u_s[r][t16 * 4]) = u0;
            *reinterpret_cast<float4*>(arow + j0 + t16 * 4) = u0;
        }
        __syncthreads();
        // acc[dv pair] += p[r][jj] * v[jj][dv]
        #pragma unroll
        for (int jj = 0; jj < 64; ++jj) {
            const float ub = u_s[r][jj];                          // broadcast
            const float2 vv = *reinterpret_cast<const float2*>(&v_s[jj][t16 * 2]);
            a0 = fmaf(ub, vv.x, a0);
            a1 = fmaf(ub, vv.y, a1);
        }
    }
    *reinterpret_cast<float2*>(out + ((size_t)bh * L_ + i0 + r) * DV_ + t16 * 2)
        = make_float2(a0, a1);
}

extern "C" void kernel_launch(void* const* d_in, const int* in_sizes, int n_in,
                              void* d_out, int out_size, void* d_ws, size_t ws_size,
                              hipStream_t stream) {
    const float* q   = (const float*)d_in[0];
    const float* k   = (const float*)d_in[1];
    const float* v   = (const float*)d_in[2];
    const float* a_k = (const float*)d_in[3];

    float* out  = (float*)d_out;
    float* attn = out + (size_t)BH_ * L_ * DV_;   // out first, attn second

    float* ws   = (float*)d_ws;
    float* sums = ws;                        // 2*32*1024 floats = 256 KB
    float* qT   = ws + 2 * BH_ * L_;         // 4 MB

    transpose_q<<<dim3(128),   dim3(256), 0, stream>>>(q, qT);
    score_kernel<<<dim3(1024), dim3(256), 0, stream>>>(qT, k, a_k, attn, sums);
    pv_kernel<<<dim3(2048),    dim3(256), 0, stream>>>(v, sums, attn, out);
}

// Round 4
// 408.397 us; speedup vs baseline: 1.2765x; 1.0126x over previous
//
#include <hip/hip_runtime.h>
#include <cstddef>

// Problem constants (fixed by setup_inputs)
#define B_  4
#define L_  1024
#define H_  8
#define DK_ 32
#define DV_ 32
#define BH_ 32            // B_*H_
#define HD_ 256           // H_*DK_

#define INV_T 0.17677669529663687f  // 1/sqrt(32)

// ---------------------------------------------------------------------------
// Kernel 0: transpose q[b, j, h*32+d] -> qT[bh][d4][j][c]  (c = d%4)
// grid 128 = bh(32) x jt(4), 256 threads
// ---------------------------------------------------------------------------
__global__ __launch_bounds__(256) void transpose_q(
    const float* __restrict__ q, float* __restrict__ qT)
{
    const int bh  = blockIdx.x >> 2;
    const int jt  = blockIdx.x & 3;
    const int b   = bh >> 3, h = bh & 7;
    const int tid = threadIdx.x;

    __shared__ float t_s[256][33];

    const float* qb = q + (size_t)b * L_ * HD_ + h * DK_;
    #pragma unroll
    for (int rep = 0; rep < 8; ++rep) {
        const int f = rep * 1024 + tid * 4;
        const int j = f >> 5, d = f & 31;
        float4 val = *reinterpret_cast<const float4*>(qb + (size_t)(jt * 256 + j) * HD_ + d);
        t_s[j][d + 0] = val.x; t_s[j][d + 1] = val.y;
        t_s[j][d + 2] = val.z; t_s[j][d + 3] = val.w;
    }
    __syncthreads();
    // qT[bh][d4][j][c] : bh*32768 + d4*4096 + j*4 + c
    float* qo = qT + (size_t)bh * (DK_ * L_);
    const int j = jt * 256 + tid;
    #pragma unroll
    for (int d4 = 0; d4 < 8; ++d4) {
        float4 w = make_float4(t_s[tid][d4 * 4 + 0], t_s[tid][d4 * 4 + 1],
                               t_s[tid][d4 * 4 + 2], t_s[tid][d4 * 4 + 3]);
        *reinterpret_cast<float4*>(qo + (size_t)d4 * (L_ * 4) + (size_t)j * 4) = w;
    }
}

// ---------------------------------------------------------------------------
// Kernel 1: scores. grid 2048 = ig(512: 2 i-rows) x half(2) x jhalf(2).
// Block: 2 i's x 16 bh x 512 j's. 256 thr = 4 waves; wave w -> bh w*4..w*4+3.
// LDS halved to 18.4 KB -> 8 blocks/CU = 100% wave occupancy (latency hiding).
// k is wave-uniform -> scalar loads. a_k demand-staged -> LDS (proven).
// Writes u = exp(score/T) + per-row partial sums (per jhalf).
// ---------------------------------------------------------------------------
__global__ __launch_bounds__(256) void score_kernel(
    const float* __restrict__ qT,
    const float* __restrict__ k,
    const float* __restrict__ a_k,
    float* __restrict__ attn_u,
    float* __restrict__ sums)   // [2][BH_][L_] partials
{
    const int bidx  = blockIdx.x;
    const int jhalf = bidx & 1;
    const int half  = (bidx >> 1) & 1;
    const int ig    = bidx >> 2;          // 0..511
    const int i0    = ig * 2;
    const int bh0   = half * 16;
    const int tid   = threadIdx.x;
    const int w     = __builtin_amdgcn_readfirstlane(tid >> 6);  // wave-uniform
    const int lane  = tid & 63;

    __shared__ float a_s[2][64][36];   // [ii][jj][d] pad 36 — 18,432 B

    float rs[4][2] = {{0.f}};          // [bhl][ii] row-sum partials

    for (int jt = jhalf * 8; jt < jhalf * 8 + 8; ++jt) {
        const int j0 = jt * 64;
        __syncthreads();
        #pragma unroll
        for (int rep = 0; rep < 4; ++rep) {
            const int f  = rep * 1024 + tid * 4;
            const int ii = f >> 11, jj = (f >> 5) & 63, d = f & 31;
            float4 val = *reinterpret_cast<const float4*>(
                a_k + (size_t)(i0 + ii) * (L_ * DK_) + (size_t)(j0 + jj) * DK_ + d);
            *reinterpret_cast<float4*>(&a_s[ii][jj][d]) = val;
        }
        __syncthreads();

        float s[4][2];
        #pragma unroll
        for (int bhl = 0; bhl < 4; ++bhl)
            #pragma unroll
            for (int ii = 0; ii < 2; ++ii) s[bhl][ii] = 0.f;

        #pragma unroll 2
        for (int d4 = 0; d4 < 8; ++d4) {
            float4 av[2];
            #pragma unroll
            for (int ii = 0; ii < 2; ++ii)
                av[ii] = *reinterpret_cast<const float4*>(&a_s[ii][lane][d4 * 4]);
            #pragma unroll
            for (int bhl = 0; bhl < 4; ++bhl) {
                const int bh = bh0 + w * 4 + bhl;      // wave-uniform
                const int b  = bh >> 3, h = bh & 7;
                // qT[bh][d4][j][c] — one dwordx4 per (d4, bhl)
                const float4 q4 = *reinterpret_cast<const float4*>(
                    qT + (size_t)bh * (DK_ * L_) + (size_t)d4 * (L_ * 4) + (size_t)(j0 + lane) * 4);
                const float* kp = k + (size_t)b * L_ * HD_ + (size_t)i0 * HD_ + h * DK_ + d4 * 4;
                #pragma unroll
                for (int ii = 0; ii < 2; ++ii) {
                    float4 kv = *reinterpret_cast<const float4*>(kp + ii * HD_);  // s_load
                    s[bhl][ii] = fmaf(kv.x * av[ii].x, q4.x, s[bhl][ii]);
                    s[bhl][ii] = fmaf(kv.y * av[ii].y, q4.y, s[bhl][ii]);
                    s[bhl][ii] = fmaf(kv.z * av[ii].z, q4.z, s[bhl][ii]);
                    s[bhl][ii] = fmaf(kv.w * av[ii].w, q4.w, s[bhl][ii]);
                }
            }
        }

        #pragma unroll
        for (int bhl = 0; bhl < 4; ++bhl) {
            const int bh = bh0 + w * 4 + bhl;
            #pragma unroll
            for (int ii = 0; ii < 2; ++ii) {
                const float u = __expf(s[bhl][ii] * INV_T);
                rs[bhl][ii] += u;
                attn_u[((size_t)bh * L_ + (i0 + ii)) * L_ + j0 + lane] = u;
            }
        }
    }

    #pragma unroll
    for (int bhl = 0; bhl < 4; ++bhl) {
        #pragma unroll
        for (int ii = 0; ii < 2; ++ii) {
            float vsum = rs[bhl][ii];
            #pragma unroll
            for (int off = 32; off > 0; off >>= 1) vsum += __shfl_xor(vsum, off);
            if (lane == 0)
                sums[((size_t)jhalf * BH_ + bh0 + w * 4 + bhl) * L_ + i0 + ii] = vsum;
        }
    }
}

// ---------------------------------------------------------------------------
// Kernel 2: normalize + PV. grid 2048 = bh(32) x ic(64: 16 i-rows each).
// 256 thr: r = tid>>4 (row 0..15), t16 = tid&15.  (round-1 proven structure;
// inner loop now reads u via b128: LDS instrs per jt 128 -> 80)
// ---------------------------------------------------------------------------
__global__ __launch_bounds__(256) void pv_kernel(
    const float* __restrict__ v,
    const float* __restrict__ sums,
    float* __restrict__ attn,    // u on entry, p on exit
    float* __restrict__ out)
{
    const int bh  = blockIdx.x >> 6;
    const int ic  = blockIdx.x & 63;
    const int i0  = ic * 16;
    const int b   = bh >> 3, h = bh & 7;
    const int tid = threadIdx.x;
    const int r   = tid >> 4;
    const int t16 = tid & 15;

    __shared__ float v_s[64][36];    // [jj][dv] pad 36
    __shared__ float u_s[16][68];    // pad 68 (17x16B): b128-aligned rows

    const float inv = 1.0f / (sums[(size_t)bh * L_ + i0 + r] +
                              sums[(size_t)(BH_ + bh) * L_ + i0 + r]);
    float* arow = attn + ((size_t)bh * L_ + i0 + r) * L_;

    float a0 = 0.f, a1 = 0.f;

    for (int jt = 0; jt < 16; ++jt) {
        const int j0 = jt * 64;
        __syncthreads();
        {   // stage v tile (64 x 32)
            const int jj = tid >> 2, dv = (tid & 3) * 8;
            const float* vp = v + (size_t)b * L_ * HD_ + (size_t)(j0 + jj) * HD_ + h * DV_ + dv;
            float4 v0 = *reinterpret_cast<const float4*>(vp);
            float4 v1 = *reinterpret_cast<const float4*>(vp + 4);
            *reinterpret_cast<float4*>(&v_s[jj][dv])     = v0;
            *reinterpret_cast<float4*>(&v_s[jj][dv + 4]) = v1;
        }
        {   // stage u tile normalized; write p back
            float4 u0 = *reinterpret_cast<const float4*>(arow + j0 + t16 * 4);
            u0.x *= inv; u0.y *= inv; u0.z *= inv; u0.w *= inv;
            *reinterpret_cast<float4*>(&u_s[r][t16 * 4]) = u0;
            *reinterpret_cast<float4*>(arow + j0 + t16 * 4) = u0;
        }
        __syncthreads();
        // acc[dv pair] += p[r][jj] * v[jj][dv] — u read 4-at-a-time (b128)
        #pragma unroll
        for (int jj4 = 0; jj4 < 16; ++jj4) {
            const float4 u4 = *reinterpret_cast<const float4*>(&u_s[r][jj4 * 4]);
            const float2 vv0 = *reinterpret_cast<const float2*>(&v_s[jj4 * 4 + 0][t16 * 2]);
            const float2 vv1 = *reinterpret_cast<const float2*>(&v_s[jj4 * 4 + 1][t16 * 2]);
            const float2 vv2 = *reinterpret_cast<const float2*>(&v_s[jj4 * 4 + 2][t16 * 2]);
            const float2 vv3 = *reinterpret_cast<const float2*>(&v_s[jj4 * 4 + 3][t16 * 2]);
            a0 = fmaf(u4.x, vv0.x, a0); a1 = fmaf(u4.x, vv0.y, a1);
            a0 = fmaf(u4.y, vv1.x, a0); a1 = fmaf(u4.y, vv1.y, a1);
            a0 = fmaf(u4.z, vv2.x, a0); a1 = fmaf(u4.z, vv2.y, a1);
            a0 = fmaf(u4.w, vv3.x, a0); a1 = fmaf(u4.w, vv3.y, a1);
        }
    }
    *reinterpret_cast<float2*>(out + ((size_t)bh * L_ + i0 + r) * DV_ + t16 * 2)
        = make_float2(a0, a1);
}

extern "C" void kernel_launch(void* const* d_in, const int* in_sizes, int n_in,
                              void* d_out, int out_size, void* d_ws, size_t ws_size,
                              hipStream_t stream) {
    const float* q   = (const float*)d_in[0];
    const float* k   = (const float*)d_in[1];
    const float* v   = (const float*)d_in[2];
    const float* a_k = (const float*)d_in[3];

    float* out  = (float*)d_out;
    float* attn = out + (size_t)BH_ * L_ * DV_;   // out first, attn second

    float* ws   = (float*)d_ws;
    float* sums = ws;                        // 2*32*1024 floats = 256 KB
    float* qT   = ws + 2 * BH_ * L_;         // 4 MB

    transpose_q<<<dim3(128),   dim3(256), 0, stream>>>(q, qT);
    score_kernel<<<dim3(2048), dim3(256), 0, stream>>>(qT, k, a_k, attn, sums);
    pv_kernel<<<dim3(2048),    dim3(256), 0, stream>>>(v, sums, attn, out);
}